// Round 1
// baseline (103.774 us; speedup 1.0000x reference)
//
#include <hip/hip_runtime.h>
#include <math.h>

// Barrier_Net: deep-sets net + barrier term + global max-rescale.
// BATCH=4096, 66 blocks of 4 state dims, phi: 4->256->64 (summed over 66),
// rho: 64->256->2, a = 2*tanh(.) + barrier, scale = 2/max(a) applied if <1.
//
// Fusion: sum relu-hidden over n BEFORE the 256->64 matmul (linearity),
// cutting phase-2 from 4.4G to 67M MACs. All fp32 VALU (K=4 too small for
// MFMA; fp32 keeps us far under the 4e-2 absolute threshold).

#define GROWS 8          // batch rows per block
#define NBLOCKS (4096 / GROWS)

__device__ __forceinline__ unsigned fkey(float f) {
    // monotonic float->unsigned mapping: key(a) < key(b) iff a < b.
    unsigned u = __float_as_uint(f);
    return (u & 0x80000000u) ? ~u : (u | 0x80000000u);
}
__device__ __forceinline__ float fkey_inv(unsigned k) {
    return __uint_as_float((k & 0x80000000u) ? (k & 0x7fffffffu) : ~k);
}

__global__ __launch_bounds__(256) void barrier_net_main(
    const float* __restrict__ x,
    const float* __restrict__ w1,  const float* __restrict__ b1,
    const float* __restrict__ w2,  const float* __restrict__ b2,
    const float* __restrict__ rw1, const float* __restrict__ rb1,
    const float* __restrict__ rw2, const float* __restrict__ rb2,
    float* __restrict__ out, unsigned* __restrict__ maxkey)
{
    __shared__ float sx[GROWS][264];    // x tile
    __shared__ float sH[GROWS][256];    // sum_n relu(h_n)
    __shared__ float sX[GROWS][64];     // phi-sum
    __shared__ float sh2[GROWS][256];   // rho hidden
    __shared__ float sbar[GROWS][2];    // barrier terms
    __shared__ float sa[GROWS * 2];     // final a (pre-scale) for block max

    const int tid  = threadIdx.x;
    const int lane = tid & 63;
    const int wv   = tid >> 6;          // wave id 0..3
    const int b0   = blockIdx.x * GROWS;

    // ---- stage x tile (GROWS*264 = 2112 floats) ----
    for (int i = tid; i < GROWS * 264; i += 256) {
        int r = i / 264, c = i % 264;
        sx[r][c] = x[(b0 + r) * 264 + c];
    }
    __syncthreads();

    // ---- phase 1: per-hidden-unit accumulate over 66 blocks ----
    float w[4];
    w[0] = w1[tid]; w[1] = w1[256 + tid]; w[2] = w1[512 + tid]; w[3] = w1[768 + tid];
    const float bias = b1[tid];
    for (int r = 0; r < GROWS; r++) {
        float acc = 0.f;
        #pragma unroll
        for (int n = 0; n < 66; n++) {
            float h = bias;
            h = fmaf(sx[r][n * 4 + 0], w[0], h);
            h = fmaf(sx[r][n * 4 + 1], w[1], h);
            h = fmaf(sx[r][n * 4 + 2], w[2], h);
            h = fmaf(sx[r][n * 4 + 3], w[3], h);
            acc += fmaxf(h, 0.f);
        }
        sH[r][tid] = acc;
    }

    // ---- barrier term: rows split 2-per-wave, neighbors n=2..65 over lanes ----
    #pragma unroll
    for (int rr = 0; rr < 2; rr++) {
        int r = wv * 2 + rr;
        float px = sx[r][(lane + 2) * 4 + 0];
        float py = sx[r][(lane + 2) * 4 + 1];
        float d  = sqrtf(px * px + py * py);
        float t  = d - 0.15f;
        float inv = 1.0f / (t * t);
        float bx = -px * inv, by = -py * inv;
        #pragma unroll
        for (int m = 32; m >= 1; m >>= 1) {
            bx += __shfl_xor(bx, m);
            by += __shfl_xor(by, m);
        }
        if (lane == 0) { sbar[r][0] = bx; sbar[r][1] = by; }
    }
    __syncthreads();

    // ---- phase 2: X[r][o] = sum_k sH[r][k]*W2[k][o] + 66*b2[o] ----
    {
        const int o  = tid & 63;
        const int rg = tid >> 6;        // 2 rows per thread
        float a0 = 0.f, a1 = 0.f;
        #pragma unroll 8
        for (int k = 0; k < 256; k++) {
            float wk = w2[k * 64 + o];
            a0 = fmaf(sH[rg * 2 + 0][k], wk, a0);
            a1 = fmaf(sH[rg * 2 + 1][k], wk, a1);
        }
        float bb = 66.0f * b2[o];
        sX[rg * 2 + 0][o] = a0 + bb;
        sX[rg * 2 + 1][o] = a1 + bb;
    }
    __syncthreads();

    // ---- phase 3: h2[r][tid] = relu(sum_o X[r][o]*rw1[o][tid] + rb1[tid]) ----
    {
        float acc3[GROWS];
        #pragma unroll
        for (int r = 0; r < GROWS; r++) acc3[r] = rb1[tid];
        for (int o4 = 0; o4 < 16; o4++) {
            float wv3[4];
            #pragma unroll
            for (int j = 0; j < 4; j++) wv3[j] = rw1[(o4 * 4 + j) * 256 + tid];
            #pragma unroll
            for (int r = 0; r < GROWS; r++) {
                float4 xv = ((const float4*)sX[r])[o4];
                acc3[r] = fmaf(xv.x, wv3[0], acc3[r]);
                acc3[r] = fmaf(xv.y, wv3[1], acc3[r]);
                acc3[r] = fmaf(xv.z, wv3[2], acc3[r]);
                acc3[r] = fmaf(xv.w, wv3[3], acc3[r]);
            }
        }
        #pragma unroll
        for (int r = 0; r < GROWS; r++) sh2[r][tid] = fmaxf(acc3[r], 0.f);
    }
    __syncthreads();

    // ---- phase 4: pre[r][k] = sum_j h2[r][j]*rw2[j][k]; a = 2*tanh + barrier ----
    {
        const int grp = tid >> 5;       // row, 32 lanes per row
        const int gl  = tid & 31;
        float p0 = 0.f, p1 = 0.f;
        const float2* rw2v = (const float2*)rw2;
        #pragma unroll
        for (int i = 0; i < 8; i++) {
            int j = gl + 32 * i;
            float  h  = sh2[grp][j];
            float2 wk = rw2v[j];
            p0 = fmaf(h, wk.x, p0);
            p1 = fmaf(h, wk.y, p1);
        }
        #pragma unroll
        for (int m = 16; m >= 1; m >>= 1) {
            p0 += __shfl_xor(p0, m);
            p1 += __shfl_xor(p1, m);
        }
        if (gl == 0) {
            float a0 = 2.0f * tanhf(p0 + rb2[0]) + sbar[grp][0];
            float a1 = 2.0f * tanhf(p1 + rb2[1]) + sbar[grp][1];
            out[(b0 + grp) * 2 + 0] = a0;
            out[(b0 + grp) * 2 + 1] = a1;
            sa[grp * 2 + 0] = a0;
            sa[grp * 2 + 1] = a1;
        }
    }
    __syncthreads();

    if (tid == 0) {
        float m = sa[0];
        #pragma unroll
        for (int i = 1; i < GROWS * 2; i++) m = fmaxf(m, sa[i]);
        atomicMax(maxkey, fkey(m));
    }
}

__global__ __launch_bounds__(256) void barrier_net_scale(
    float* __restrict__ out, const unsigned* __restrict__ maxkey)
{
    int i = blockIdx.x * 256 + threadIdx.x;
    float amax  = fkey_inv(*maxkey);
    float scale = 2.0f / amax;
    float a = out[i];
    out[i] = (scale < 1.0f) ? a * scale : a;
}

extern "C" void kernel_launch(void* const* d_in, const int* in_sizes, int n_in,
                              void* d_out, int out_size, void* d_ws, size_t ws_size,
                              hipStream_t stream) {
    const float* x   = (const float*)d_in[0];
    const float* w1  = (const float*)d_in[1];
    const float* b1  = (const float*)d_in[2];
    const float* w2  = (const float*)d_in[3];
    const float* b2  = (const float*)d_in[4];
    const float* rw1 = (const float*)d_in[5];
    const float* rb1 = (const float*)d_in[6];
    const float* rw2 = (const float*)d_in[7];
    const float* rb2 = (const float*)d_in[8];
    float* out = (float*)d_out;
    unsigned* maxkey = (unsigned*)d_ws;

    // key 0 is below key(-inf) in the monotonic mapping -> identity for max.
    hipMemsetAsync(d_ws, 0, 4, stream);
    barrier_net_main<<<NBLOCKS, 256, 0, stream>>>(
        x, w1, b1, w2, b2, rw1, rb1, rw2, rb2, out, maxkey);
    barrier_net_scale<<<8192 / 256, 256, 0, stream>>>(out, maxkey);
}

// Round 2
// 98.677 us; speedup vs baseline: 1.0516x; 1.0516x over previous
//
#include <hip/hip_runtime.h>
#include <math.h>

// Barrier_Net: deep-sets net + barrier + global max-rescale.
// Key insight from round 1: the kernel was LDS-pipe-bound (VALUBusy 31%) —
// every wave redundantly broadcast the same x/H/X values from LDS
// (~100K LDS instrs/CU ≈ 40 µs of per-CU LDS pipe). This version keeps
// wave-shared data OFF the LDS pipe: x via wave-uniform (scalar-path)
// global loads, H/X broadcasts via v_readlane through SGPRs (VALU pipe).
// LDS is used only for the cheap cross-wave transposes/reductions.

#define GROWS 4
#define NBLOCKS (4096 / GROWS)   // 1024 blocks -> 4 blocks/CU, 16 waves/CU

__device__ __forceinline__ unsigned fkey(float f) {
    unsigned u = __float_as_uint(f);
    return (u & 0x80000000u) ? ~u : (u | 0x80000000u);
}
__device__ __forceinline__ float fkey_inv(unsigned k) {
    return __uint_as_float((k & 0x80000000u) ? (k & 0x7fffffffu) : ~k);
}
__device__ __forceinline__ float rlane(float v, int i) {
    return __uint_as_float(__builtin_amdgcn_readlane(__float_as_uint(v), i));
}

__global__ __launch_bounds__(256, 4) void barrier_net_main(
    const float* __restrict__ x,
    const float* __restrict__ w1,  const float* __restrict__ b1,
    const float* __restrict__ w2,  const float* __restrict__ b2,
    const float* __restrict__ rw1, const float* __restrict__ rb1,
    const float* __restrict__ rw2, const float* __restrict__ rb2,
    float* __restrict__ out, unsigned* __restrict__ maxkey)
{
    __shared__ float sH[GROWS][264];     // H rows (256 + pad 8: rows offset 8 banks)
    __shared__ float sXp[4][GROWS][68];  // [wave][row][o] phase-2 partials (padded)
    __shared__ float sP4[4][GROWS][2];   // [wave][row][c] phase-4 partials
    __shared__ float sbar[GROWS][2];     // barrier terms
    __shared__ float sa[GROWS * 2];      // final a for block max

    const int tid = threadIdx.x;
    const int ln  = tid & 63;
    const int wv  = tid >> 6;
    const int b0  = blockIdx.x * GROWS;
    // wave <-> row; readfirstlane makes the row provably wave-uniform so the
    // x loads can take the scalar (SMEM) path instead of LDS/VMEM broadcast.
    const int row = __builtin_amdgcn_readfirstlane(b0 + wv);
    const float4* __restrict__ x4 = (const float4*)(x + (size_t)row * 264);

    // ---- phase 1: H[row][4ln..4ln+3] = sum_n relu(x_n . w1 + b1) ----
    float4 w1r0 = ((const float4*)(w1      ))[ln];
    float4 w1r1 = ((const float4*)(w1 + 256))[ln];
    float4 w1r2 = ((const float4*)(w1 + 512))[ln];
    float4 w1r3 = ((const float4*)(w1 + 768))[ln];
    float4 b1r  = ((const float4*)b1)[ln];
    float a0 = 0.f, a1 = 0.f, a2 = 0.f, a3 = 0.f;
    #pragma unroll 6
    for (int n = 0; n < 66; n++) {
        float4 xv = x4[n];   // wave-uniform address -> s_load
        float h0 = b1r.x, h1 = b1r.y, h2 = b1r.z, h3 = b1r.w;
        h0 = fmaf(xv.x, w1r0.x, h0); h1 = fmaf(xv.x, w1r0.y, h1);
        h2 = fmaf(xv.x, w1r0.z, h2); h3 = fmaf(xv.x, w1r0.w, h3);
        h0 = fmaf(xv.y, w1r1.x, h0); h1 = fmaf(xv.y, w1r1.y, h1);
        h2 = fmaf(xv.y, w1r1.z, h2); h3 = fmaf(xv.y, w1r1.w, h3);
        h0 = fmaf(xv.z, w1r2.x, h0); h1 = fmaf(xv.z, w1r2.y, h1);
        h2 = fmaf(xv.z, w1r2.z, h2); h3 = fmaf(xv.z, w1r2.w, h3);
        h0 = fmaf(xv.w, w1r3.x, h0); h1 = fmaf(xv.w, w1r3.y, h1);
        h2 = fmaf(xv.w, w1r3.z, h2); h3 = fmaf(xv.w, w1r3.w, h3);
        a0 += fmaxf(h0, 0.f); a1 += fmaxf(h1, 0.f);
        a2 += fmaxf(h2, 0.f); a3 += fmaxf(h3, 0.f);
    }
    ((float4*)sH[wv])[ln] = make_float4(a0, a1, a2, a3);

    // ---- barrier term: lane ln <-> neighbor n = ln+2 (exactly 64) ----
    {
        float4 pv = x4[ln + 2];          // lane-varying -> coalesced vector load
        float px = pv.x, py = pv.y;
        float d  = sqrtf(px * px + py * py);
        float t  = d - 0.15f;
        float inv = 1.0f / (t * t);
        float bx = -px * inv, by = -py * inv;
        #pragma unroll
        for (int m = 32; m >= 1; m >>= 1) {
            bx += __shfl_xor(bx, m);
            by += __shfl_xor(by, m);
        }
        if (ln == 0) { sbar[wv][0] = bx; sbar[wv][1] = by; }
    }
    __syncthreads();

    // ---- phase 2: X[r][o] = sum_k H[r][k] w2[k][o] + 66*b2[o] ----
    // wave wv owns k-quarter [64wv, 64wv+64); lane = o; H broadcast via readlane.
    float Hq0 = sH[0][(wv << 6) + ln];
    float Hq1 = sH[1][(wv << 6) + ln];
    float Hq2 = sH[2][(wv << 6) + ln];
    float Hq3 = sH[3][(wv << 6) + ln];
    {
        float xp0 = 0.f, xp1 = 0.f, xp2 = 0.f, xp3 = 0.f;
        const float* w2q = w2 + (wv << 12);   // w2[(64wv)*64]
        #pragma unroll 16
        for (int i = 0; i < 64; i++) {
            float wv2 = w2q[(i << 6) + ln];   // coalesced; w2 read once per block
            xp0 = fmaf(rlane(Hq0, i), wv2, xp0);
            xp1 = fmaf(rlane(Hq1, i), wv2, xp1);
            xp2 = fmaf(rlane(Hq2, i), wv2, xp2);
            xp3 = fmaf(rlane(Hq3, i), wv2, xp3);
        }
        sXp[wv][0][ln] = xp0; sXp[wv][1][ln] = xp1;
        sXp[wv][2][ln] = xp2; sXp[wv][3][ln] = xp3;
    }
    __syncthreads();

    // every wave folds the 4 partials -> X[r][ln] in registers
    float bb = 66.0f * b2[ln];
    float Xf0 = sXp[0][0][ln] + sXp[1][0][ln] + sXp[2][0][ln] + sXp[3][0][ln] + bb;
    float Xf1 = sXp[0][1][ln] + sXp[1][1][ln] + sXp[2][1][ln] + sXp[3][1][ln] + bb;
    float Xf2 = sXp[0][2][ln] + sXp[1][2][ln] + sXp[2][2][ln] + sXp[3][2][ln] + bb;
    float Xf3 = sXp[0][3][ln] + sXp[1][3][ln] + sXp[2][3][ln] + sXp[3][3][ln] + bb;

    // ---- phase 3: h2[r][h] = relu(sum_o X[r][o] rw1[o][h] + rb1[h]), h = tid ----
    float c0, c1, c2, c3;
    c0 = c1 = c2 = c3 = rb1[tid];
    #pragma unroll 16
    for (int i = 0; i < 64; i++) {
        float rwv = rw1[(i << 8) + tid];      // coalesced; rw1 read once per block
        c0 = fmaf(rlane(Xf0, i), rwv, c0);
        c1 = fmaf(rlane(Xf1, i), rwv, c1);
        c2 = fmaf(rlane(Xf2, i), rwv, c2);
        c3 = fmaf(rlane(Xf3, i), rwv, c3);
    }
    c0 = fmaxf(c0, 0.f); c1 = fmaxf(c1, 0.f);
    c2 = fmaxf(c2, 0.f); c3 = fmaxf(c3, 0.f);

    // ---- phase 4: pre[r][c] = sum_h h2[r][h] rw2[h][c]; butterfly over h ----
    {
        float2 r2 = ((const float2*)rw2)[tid];
        float p00 = c0 * r2.x, p01 = c0 * r2.y;
        float p10 = c1 * r2.x, p11 = c1 * r2.y;
        float p20 = c2 * r2.x, p21 = c2 * r2.y;
        float p30 = c3 * r2.x, p31 = c3 * r2.y;
        #pragma unroll
        for (int m = 32; m >= 1; m >>= 1) {
            p00 += __shfl_xor(p00, m); p01 += __shfl_xor(p01, m);
            p10 += __shfl_xor(p10, m); p11 += __shfl_xor(p11, m);
            p20 += __shfl_xor(p20, m); p21 += __shfl_xor(p21, m);
            p30 += __shfl_xor(p30, m); p31 += __shfl_xor(p31, m);
        }
        if (ln == 0) {
            sP4[wv][0][0] = p00; sP4[wv][0][1] = p01;
            sP4[wv][1][0] = p10; sP4[wv][1][1] = p11;
            sP4[wv][2][0] = p20; sP4[wv][2][1] = p21;
            sP4[wv][3][0] = p30; sP4[wv][3][1] = p31;
        }
    }
    __syncthreads();

    if (tid < GROWS * 2) {
        int r = tid >> 1, c = tid & 1;
        float pre = sP4[0][r][c] + sP4[1][r][c] + sP4[2][r][c] + sP4[3][r][c] + rb2[c];
        float a = 2.0f * tanhf(pre) + sbar[r][c];
        out[(b0 + r) * 2 + c] = a;
        sa[tid] = a;
    }
    __syncthreads();
    if (tid == 0) {
        float m = sa[0];
        #pragma unroll
        for (int i = 1; i < GROWS * 2; i++) m = fmaxf(m, sa[i]);
        atomicMax(maxkey, fkey(m));
    }
}

__global__ __launch_bounds__(256) void barrier_net_scale(
    float* __restrict__ out, const unsigned* __restrict__ maxkey)
{
    int i = blockIdx.x * 256 + threadIdx.x;
    float amax  = fkey_inv(*maxkey);
    float scale = 2.0f / amax;
    float a = out[i];
    out[i] = (scale < 1.0f) ? a * scale : a;
}

extern "C" void kernel_launch(void* const* d_in, const int* in_sizes, int n_in,
                              void* d_out, int out_size, void* d_ws, size_t ws_size,
                              hipStream_t stream) {
    const float* x   = (const float*)d_in[0];
    const float* w1  = (const float*)d_in[1];
    const float* b1  = (const float*)d_in[2];
    const float* w2  = (const float*)d_in[3];
    const float* b2  = (const float*)d_in[4];
    const float* rw1 = (const float*)d_in[5];
    const float* rb1 = (const float*)d_in[6];
    const float* rw2 = (const float*)d_in[7];
    const float* rb2 = (const float*)d_in[8];
    float* out = (float*)d_out;
    unsigned* maxkey = (unsigned*)d_ws;

    // key 0 is below key(-inf) in the monotonic mapping -> identity for max.
    hipMemsetAsync(d_ws, 0, 4, stream);
    barrier_net_main<<<NBLOCKS, 256, 0, stream>>>(
        x, w1, b1, w2, b2, rw1, rb1, rw2, rb2, out, maxkey);
    barrier_net_scale<<<8192 / 256, 256, 0, stream>>>(out, maxkey);
}